// Round 7
// baseline (275.248 us; speedup 1.0000x reference)
//
#include <hip/hip_runtime.h>
#include <math.h>

#define Bb    8
#define Tseq  2048
#define Cch   512
#define Mrows 16384
#define Nqkv  1536

typedef __bf16 bf16x8 __attribute__((ext_vector_type(8)));
typedef __bf16 bf16x4 __attribute__((ext_vector_type(4)));
typedef float  f32x4  __attribute__((ext_vector_type(4)));

__device__ __forceinline__ void gld_lds16(const void* g, void* l) {
  __builtin_amdgcn_global_load_lds(
      (const __attribute__((address_space(1))) unsigned int*)g,
      (__attribute__((address_space(3))) unsigned int*)l, 16, 0, 0);
}

// LDS bank-conflict-killing XOR swizzle: row r's 8-element group g lives at
// group (g ^ (r&7)). Verified: SQ_LDS_BANK_CONFLICT 1.26e7 -> 0.
#define SWZ(r, g) (((r) << 6) + ((((g) ^ ((r) & 7))) << 3))

// ---------------------------------------------------------------------------
// Round 13: A-operand direct-to-register (skip LDS for A) in both GEMMs.
// Rationale: R6 showed +65% occupancy -> only +1.8pt MfmaUtil; arithmetic
// says the LDS-read pipe is the long pole (48KB read per block-K-tile vs
// 24KB staged; ~26us of LDS time vs ~14us MFMA in conv). The A fragment
// (lane lm reads 8 consecutive k of row base+lm) is exactly a coalesced
// global_load_dwordx4 from the row-major source -> load A frags to VGPRs,
// keep only B in LDS. LDS reads -33%, staging loads -33%, gather branch
// leaves the hot staging loop. A re-reads (2x per block) land on L2.
// ---------------------------------------------------------------------------

// ---------------------------------------------------------------------------
// Fused QKV-projection + Wp-precompute GEMM. 128x128 tiles, B-only LDS.
// Blocks [0,1536): qkv = xb @ Wqkv_t^T + bias -> [16384][1536].
// Blocks [1536,1600): Wp[z] = Wc[z]^T-major @ Wo^T -> Wp_bt [512][2048].
// ---------------------------------------------------------------------------
__global__ __launch_bounds__(256, 2) void gemm_qkv_wp_kernel(
    const __bf16* __restrict__ xb, const __bf16* __restrict__ Wqkv_t,
    const float* __restrict__ bq, const float* __restrict__ bk,
    const float* __restrict__ bv, __bf16* __restrict__ qkv,
    const __bf16* __restrict__ Wc_t, const __bf16* __restrict__ Wob,
    __bf16* __restrict__ Wp_bt) {
  __shared__ __align__(16) __bf16 Bs[128 * 64];  // 16 KB
  const int tid = threadIdx.x;
  const int w = tid >> 6, lane = tid & 63;
  const int wm = w & 1, wn = w >> 1;
  const int lm = lane & 15, quad = lane >> 4;
  const int srow = lane >> 3;
  const int scol = (((lane & 7) ^ srow) << 3);
  const int lid = blockIdx.x;

  const __bf16 *Ap, *Bp;
  __bf16* op;
  int lda, ldo, m0, n0;
  bool dobias;
  if (lid < 1536) {
    const int xcd = lid & 7, chunk = lid >> 3;
    const int idx = xcd * 192 + chunk;
    const int mt = idx / 12, nt = idx - mt * 12;
    m0 = mt * 128; n0 = nt * 128;
    Ap = xb; lda = 512; Bp = Wqkv_t;
    op = qkv; ldo = 1536; dobias = true;
  } else {
    const int l2 = lid - 1536;
    const int z = l2 >> 4;
    m0 = ((l2 >> 2) & 3) * 128; n0 = (l2 & 3) * 128;
    Ap = Wc_t + z * 512; lda = 2048; Bp = Wob;
    op = Wp_bt + z * 512; ldo = 2048; dobias = false;
  }

  // Per-lane A-fragment row base: rows wm*64 + i*16 + lm, 8 k's at quad*8.
  const __bf16* arow[4];
#pragma unroll
  for (int i = 0; i < 4; ++i)
    arow[i] = Ap + (size_t)(m0 + wm * 64 + i * 16 + lm) * lda + quad * 8;

  f32x4 acc[4][4] = {};
  for (int k0 = 0; k0 < 512; k0 += 64) {
    // A fragments direct from global/L2 (coalesced 64B-per-row reads).
    bf16x8 af[2][4];
#pragma unroll
    for (int i = 0; i < 4; ++i) {
      af[0][i] = *(const bf16x8*)(arow[i] + k0);
      af[1][i] = *(const bf16x8*)(arow[i] + k0 + 32);
    }
    // B staging: 16 chunks of 8 rows = 128 rows.
#pragma unroll
    for (int it = 0; it < 4; ++it) {
      const int c = w * 4 + it;
      const int row = c * 8 + srow;
      gld_lds16(Bp + (size_t)(n0 + row) * 512 + k0 + scol, &Bs[c * 512]);
    }
    __syncthreads();
#pragma unroll
    for (int ks = 0; ks < 2; ++ks) {
      bf16x8 bfr[4];
#pragma unroll
      for (int j = 0; j < 4; ++j)
        bfr[j] = *(const bf16x8*)&Bs[SWZ(wn * 64 + j * 16 + lm, ks * 4 + quad)];
#pragma unroll
      for (int i = 0; i < 4; ++i)
#pragma unroll
        for (int j = 0; j < 4; ++j)
          acc[i][j] = __builtin_amdgcn_mfma_f32_16x16x32_bf16(af[ks][i], bfr[j], acc[i][j], 0, 0, 0);
    }
    __syncthreads();
  }
#pragma unroll
  for (int j = 0; j < 4; ++j) {
    const int col = n0 + wn * 64 + j * 16 + lm;
    float bias = 0.f;
    if (dobias) {
      const int s = col >> 9;
      const float* bp = (s == 0) ? bq : (s == 1 ? bk : bv);
      bias = bp[col & 511];
    }
#pragma unroll
    for (int i = 0; i < 4; ++i) {
      const int row0 = m0 + wm * 64 + i * 16 + quad * 4;
#pragma unroll
      for (int r = 0; r < 4; ++r)
        op[(size_t)(row0 + r) * ldo + col] = (__bf16)(acc[i][j][r] + bias);
    }
  }
}

// ---------------------------------------------------------------------------
// Conv (Wo folded): K=2048 GEMM on cat with row gather, BM=64 x BN=128,
// grid 1024 = 4 blocks/CU. A fragments direct-to-register (per-lane gather
// select to zeros for t+shift<0); B-only LDS (16 KB).
// Epilogue: per-tap bias suffix from bj[4][512], relu, +x (fp32), leaky_relu.
// ---------------------------------------------------------------------------
__global__ __launch_bounds__(256, 4) void conv_gemm_kernel(
    const __bf16* __restrict__ A,   // catb [16384][512]
    const __bf16* __restrict__ Bt,  // Wp_bt [512][2048]
    const float* __restrict__ bc, const float* __restrict__ bj,  // bj[4][512]
    const float* __restrict__ x, float* __restrict__ out,
    const __bf16* __restrict__ zeros) {
  __shared__ __align__(16) __bf16 Bs[128 * 64];   // 16 KB
  const int tid = threadIdx.x;
  const int w = tid >> 6, lane = tid & 63;
  const int wm = w & 1, wn = w >> 1;   // 2M x 2N wave grid; wave tile 32x64
  const int lm = lane & 15, quad = lane >> 4;
  const int srow = lane >> 3;
  const int scol = (((lane & 7) ^ srow) << 3);
  const int lid = blockIdx.y * 4 + blockIdx.x;
  const int xcd = lid & 7, chunk = lid >> 3;
  const int idx = xcd * 128 + chunk;
  const int mt = idx >> 2, nt = idx & 3;
  const int m0 = mt * 64, n0 = nt * 128;

  // Per-lane A row indices for the 2 fragments (rows wm*32 + i*16 + lm).
  int amr[2];
#pragma unroll
  for (int i = 0; i < 2; ++i) amr[i] = m0 + wm * 32 + i * 16 + lm;

  f32x4 acc[2][4] = {};
  for (int k0 = 0; k0 < 4 * Cch; k0 += 64) {
    const int jtap = k0 >> 9;
    const int shift = 4 * jtap - 12;
    const int cin0 = k0 & 511;
    // A fragments direct from global/L2 with per-lane gather select.
    bf16x8 af[2][2];
#pragma unroll
    for (int i = 0; i < 2; ++i) {
      const int m = amr[i];
      const bool valid = ((m & (Tseq - 1)) + shift) >= 0;
      const __bf16* base = valid ? (A + (size_t)(m + shift) * Cch + cin0 + quad * 8)
                                 : (zeros + quad * 8);
      af[0][i] = *(const bf16x8*)base;
      af[1][i] = *(const bf16x8*)(valid ? base + 32 : base);
    }
    // B staging: 16 chunks of 8 rows = 128 rows.
#pragma unroll
    for (int it = 0; it < 4; ++it) {
      const int c = w * 4 + it;
      const int row = c * 8 + srow;
      gld_lds16(Bt + (size_t)(n0 + row) * 2048 + k0 + scol, &Bs[c * 512]);
    }
    __syncthreads();
#pragma unroll
    for (int ks = 0; ks < 2; ++ks) {
      bf16x8 bfr[4];
#pragma unroll
      for (int j = 0; j < 4; ++j)
        bfr[j] = *(const bf16x8*)&Bs[SWZ(wn * 64 + j * 16 + lm, ks * 4 + quad)];
#pragma unroll
      for (int i = 0; i < 2; ++i)
#pragma unroll
        for (int j = 0; j < 4; ++j)
          acc[i][j] = __builtin_amdgcn_mfma_f32_16x16x32_bf16(af[ks][i], bfr[j], acc[i][j], 0, 0, 0);
    }
    __syncthreads();
  }
#pragma unroll
  for (int j = 0; j < 4; ++j) {
    const int col = n0 + wn * 64 + j * 16 + lm;
    const float bcv = bc[col];
    float suf[4];
    suf[3] = bj[3 * 512 + col];
    suf[2] = suf[3] + bj[2 * 512 + col];
    suf[1] = suf[2] + bj[1 * 512 + col];
    suf[0] = suf[1] + bj[0 * 512 + col];
#pragma unroll
    for (int i = 0; i < 2; ++i) {
      const int row0 = m0 + wm * 32 + i * 16 + quad * 4;
#pragma unroll
      for (int r = 0; r < 4; ++r) {
        const int row = row0 + r;
        const int tl = row & (Tseq - 1);
        int jm = 15 - tl;
        jm = (jm < 0) ? 0 : (jm >> 2);
        float v = acc[i][j][r] + bcv + suf[jm];
        v = fmaxf(v, 0.f);
        v += x[(size_t)row * Cch + col];
        out[(size_t)row * Cch + col] = (v >= 0.f) ? v : 0.2f * v;
      }
    }
  }
}

// ---------------------------------------------------------------------------
// Banded attention, LDS-staged: one block per (b,h) x 64-t strip. Stage the
// 70 k-rows and 70 v-rows the strip needs into LDS once (35 KB), then 16-lane
// groups compute 4 t's each from LDS.
// ---------------------------------------------------------------------------
__global__ __launch_bounds__(256) void attn_band_kernel(
    const __bf16* __restrict__ qkv, __bf16* __restrict__ cat) {
  __shared__ __align__(16) __bf16 ks[70 * 128];
  __shared__ __align__(16) __bf16 vs[70 * 128];
  const int tid = threadIdx.x;
  const int bh = blockIdx.y;
  const int b = bh >> 2, h = bh & 3;
  const int t0 = blockIdx.x * 64;
  for (int c = tid; c < 70 * 16; c += 256) {
    const int row = c >> 4, chunk = c & 15;
    int s = t0 - 3 + row;
    s = (s < 0) ? 0 : ((s > Tseq - 1) ? Tseq - 1 : s);
    const __bf16* src = qkv + ((size_t)(b * Tseq + s)) * Nqkv + 512 + h * 128 + chunk * 8;
    *(bf16x8*)&ks[row * 128 + chunk * 8] = *(const bf16x8*)src;
    *(bf16x8*)&vs[row * 128 + chunk * 8] = *(const bf16x8*)(src + 512);
  }
  __syncthreads();
  const int g = tid & 15, grp = tid >> 4;
  const int d0 = g * 8;
  const float scale = 0.08838834764831845f;  // 1/sqrt(128)
#pragma unroll
  for (int tt = 0; tt < 4; ++tt) {
    const int tl = grp * 4 + tt;  // local t in [0,64)
    const int t = t0 + tl;
    bf16x8 qv = *(const bf16x8*)(qkv + ((size_t)(b * Tseq + t)) * Nqkv + h * 128 + d0);
    float score[7];
#pragma unroll
    for (int i = 0; i < 7; ++i) {
      const int s = t - 3 + i;
      const bool valid = (s >= 0) && (s < Tseq);
      bf16x8 kv = *(const bf16x8*)&ks[(tl + i) * 128 + d0];
      float p = 0.f;
#pragma unroll
      for (int e = 0; e < 8; ++e) p += (float)qv[e] * (float)kv[e];
      p += __shfl_xor(p, 1);
      p += __shfl_xor(p, 2);
      p += __shfl_xor(p, 4);
      p += __shfl_xor(p, 8);
      score[i] = valid ? p * scale : -1e30f;
    }
    float mx = score[0];
#pragma unroll
    for (int i = 1; i < 7; ++i) mx = fmaxf(mx, score[i]);
    float wgt[7], denom = 0.f;
#pragma unroll
    for (int i = 0; i < 7; ++i) {
      wgt[i] = (score[i] > -1e29f) ? expf(score[i] - mx) : 0.f;
      denom += wgt[i];
    }
    const float inv = 1.f / denom;
    float o[8] = {};
#pragma unroll
    for (int i = 0; i < 7; ++i) {
      bf16x8 vv = *(const bf16x8*)&vs[(tl + i) * 128 + d0];
#pragma unroll
      for (int e = 0; e < 8; ++e) o[e] += wgt[i] * (float)vv[e];
    }
    bf16x8 ov;
#pragma unroll
    for (int e = 0; e < 8; ++e) ov[e] = (__bf16)(o[e] * inv);
    *(bf16x8*)(cat + ((size_t)(b * Tseq + t)) * Cch + h * 128 + d0) = ov;
  }
}

// ---------------------------------------------------------------------------
// ONE prep kernel (flat grid):
//  [0,8192)       cast x -> xb (bf16)
//  [8192,8960)    transpose-cast Wq/Wk/Wv -> Wqkv_t [1536][512]
//  [8960,9984)    transpose-cast Wc (2048x512) -> Wc_t [512][2048]
//  [9984,10240)   cast Wo -> Wob (row-major)
//  10240          zero-fill zeros buffer
//  [10241,10273)  bias partials bj[j][n] = sum_ci bo[ci]*Wc[j,ci,n]
// ---------------------------------------------------------------------------
#define PREP_A 8192
#define PREP_B 8960
#define PREP_C 9984
#define PREP_D 10240
#define PREP_E 10241
#define PREP_N 10273

__global__ __launch_bounds__(256) void prep_kernel(
    const float* __restrict__ x, const float* __restrict__ Wq,
    const float* __restrict__ Wk, const float* __restrict__ Wv,
    const float* __restrict__ Wo, const float* __restrict__ Wc,
    const float* __restrict__ bo,
    __bf16* __restrict__ xb, __bf16* __restrict__ Wqkv_t,
    __bf16* __restrict__ Wc_t, __bf16* __restrict__ Wob,
    float* __restrict__ bj, __bf16* __restrict__ zeros) {
  __shared__ float sArr[32][33];
  __shared__ float red[256];
  const int bid = blockIdx.x;
  const int tid = threadIdx.x;
  if (bid < PREP_A) {
    const size_t i = ((size_t)bid * 256 + tid) * 4;
    float4 v = *(const float4*)(x + i);
    bf16x4 o;
    o[0] = (__bf16)v.x; o[1] = (__bf16)v.y; o[2] = (__bf16)v.z; o[3] = (__bf16)v.w;
    *(bf16x4*)(xb + i) = o;
  } else if (bid < PREP_B) {
    const int l = bid - PREP_A;
    const int bx = l & 3, by = (l >> 2) & 15, z = l >> 6;
    const int sgrp = z >> 2, h = z & 3;
    const float* src = ((sgrp == 0) ? Wq : (sgrp == 1) ? Wk : Wv) + h * (512 * 128);
    __bf16* dst = Wqkv_t + (size_t)z * 128 * 512;
    const int tx = tid & 31, ty = tid >> 5;
    const int c0 = bx * 32, r0 = by * 32;
#pragma unroll
    for (int rr = 0; rr < 4; ++rr)
      sArr[ty + rr * 8][tx] = src[(size_t)(r0 + ty + rr * 8) * 128 + c0 + tx];
    __syncthreads();
#pragma unroll
    for (int rr = 0; rr < 4; ++rr)
      dst[(size_t)(c0 + ty + rr * 8) * 512 + r0 + tx] = (__bf16)sArr[tx][ty + rr * 8];
  } else if (bid < PREP_C) {
    const int l = bid - PREP_B;
    const int bx = l & 15, by = l >> 4;
    const int tx = tid & 31, ty = tid >> 5;
    const int c0 = bx * 32, r0 = by * 32;
#pragma unroll
    for (int rr = 0; rr < 4; ++rr)
      sArr[ty + rr * 8][tx] = Wc[(size_t)(r0 + ty + rr * 8) * 512 + c0 + tx];
    __syncthreads();
#pragma unroll
    for (int rr = 0; rr < 4; ++rr)
      Wc_t[(size_t)(c0 + ty + rr * 8) * 2048 + r0 + tx] = (__bf16)sArr[tx][ty + rr * 8];
  } else if (bid < PREP_D) {
    const int l = bid - PREP_C;
    const size_t i = ((size_t)l * 256 + tid) * 4;
    float4 v = *(const float4*)(Wo + i);
    bf16x4 o;
    o[0] = (__bf16)v.x; o[1] = (__bf16)v.y; o[2] = (__bf16)v.z; o[3] = (__bf16)v.w;
    *(bf16x4*)(Wob + i) = o;
  } else if (bid < PREP_E) {
    bf16x8 zero = {};
    *(bf16x8*)(zeros + tid * 8) = zero;
  } else {
    const int l = bid - PREP_E;
    const int j = l >> 3, nb = l & 7;
    const int n = nb * 64 + (tid & 63);
    const int cig = tid >> 6;
    const float* base = Wc + ((size_t)j * 512 + cig * 128) * 512 + n;
    float acc = 0.f;
#pragma unroll 8
    for (int ci = 0; ci < 128; ++ci) acc += bo[cig * 128 + ci] * base[(size_t)ci * 512];
    red[tid] = acc;
    __syncthreads();
    if (tid < 64)
      bj[j * 512 + n] = red[tid] + red[tid + 64] + red[tid + 128] + red[tid + 192];
  }
}

// ---------------------------------------------------------------------------
extern "C" void kernel_launch(void* const* d_in, const int* in_sizes, int n_in,
                              void* d_out, int out_size, void* d_ws, size_t ws_size,
                              hipStream_t stream) {
  const float* x  = (const float*)d_in[0];
  const float* Wq = (const float*)d_in[1];
  const float* bq = (const float*)d_in[2];
  const float* Wk = (const float*)d_in[3];
  const float* bk = (const float*)d_in[4];
  const float* Wv = (const float*)d_in[5];
  const float* bv = (const float*)d_in[6];
  const float* Wo = (const float*)d_in[7];
  const float* bo = (const float*)d_in[8];
  const float* Wc = (const float*)d_in[9];
  const float* bc = (const float*)d_in[10];
  float* out = (float*)d_out;

  char* p = (char*)d_ws;
  __bf16* xb     = (__bf16*)p;  p += (size_t)Mrows * Cch * 2;    // 16 MiB
  __bf16* qkv    = (__bf16*)p;  p += (size_t)Mrows * Nqkv * 2;   // 48 MiB
  __bf16* catb   = (__bf16*)p;  p += (size_t)Mrows * Cch * 2;    // 16 MiB
  __bf16* Wqkv_t = (__bf16*)p;  p += (size_t)Nqkv * Cch * 2;     // 1.5 MiB
  __bf16* Wc_t   = (__bf16*)p;  p += (size_t)Cch * 2048 * 2;     // 2 MiB
  __bf16* Wob    = (__bf16*)p;  p += (size_t)Cch * Cch * 2;      // 0.5 MiB
  __bf16* Wp_bt  = (__bf16*)p;  p += (size_t)Cch * 2048 * 2;     // 2 MiB
  float*  bj     = (float*)p;   p += 4 * Cch * 4;                // 8 KiB
  __bf16* zeros  = (__bf16*)p;  p += 4096;

  prep_kernel<<<PREP_N, 256, 0, stream>>>(x, Wq, Wk, Wv, Wo, Wc, bo,
                                          xb, Wqkv_t, Wc_t, Wob, bj, zeros);

  // QKV projection + Wp = Wo @ Wc[j] precompute, fused into one launch
  gemm_qkv_wp_kernel<<<1600, 256, 0, stream>>>(xb, Wqkv_t, bq, bk, bv, qkv,
                                               Wc_t, Wob, Wp_bt);

  attn_band_kernel<<<dim3(Tseq / 64, Bb * 4), 256, 0, stream>>>(qkv, catb);

  conv_gemm_kernel<<<dim3(4, 256), 256, 0, stream>>>(
      catb, Wp_bt, bc, bj, x, out, zeros);
}

// Round 8
// 210.267 us; speedup vs baseline: 1.3090x; 1.3090x over previous
//
#include <hip/hip_runtime.h>
#include <math.h>

#define Bb    8
#define Tseq  2048
#define Cch   512
#define Mrows 16384
#define Nqkv  1536

typedef __bf16 bf16x8 __attribute__((ext_vector_type(8)));
typedef __bf16 bf16x4 __attribute__((ext_vector_type(4)));
typedef float  f32x4  __attribute__((ext_vector_type(4)));

__device__ __forceinline__ void gld_lds16(const void* g, void* l) {
  __builtin_amdgcn_global_load_lds(
      (const __attribute__((address_space(1))) unsigned int*)g,
      (__attribute__((address_space(3))) unsigned int*)l, 16, 0, 0);
}

// LDS bank-conflict-killing XOR swizzle: row r's 8-element group g lives at
// group (g ^ (r&7)). Verified: SQ_LDS_BANK_CONFLICT 1.26e7 -> 0.
#define SWZ(r, g) (((r) << 6) + ((((g) ^ ((r) & 7))) << 3))

// ---------------------------------------------------------------------------
// Round 14: per-kernel schedules (regime-matched).
//  - qkv (K=512, 8 tiles, latency-bound): R4's stage-early single-barrier
//    dbuf schedule. Evidence: R0->R4 differential shows it bought ~8us on
//    qkv even while hurting conv (conv +13.7us, total only +5.7us).
//  - conv (K=2048, 32 tiles, throughput regime): R6's classic 2-barrier
//    BM=64 / 4-blocks-per-CU kernel (best measured, 48.0us).
//  - R7's A-direct-to-reg REVERTED: per-lane fragment rows stride 1KB ->
//    uncoalesced VMEM, conv 89.7us, MfmaUtil 15%.
// ---------------------------------------------------------------------------

// ---------------------------------------------------------------------------
// Fused QKV-projection + Wp-precompute GEMM (R4 schedule: dbuf + stage-early
// + one vmcnt(0)+barrier per K-tile).
// Blocks [0,1536): qkv = xb @ Wqkv_t^T + bias -> [16384][1536].
// Blocks [1536,1600): Wp[z] = Wc[z]^T-major @ Wo^T -> Wp_bt [512][2048].
// ---------------------------------------------------------------------------
__global__ __launch_bounds__(256, 2) void gemm_qkv_wp_kernel(
    const __bf16* __restrict__ xb, const __bf16* __restrict__ Wqkv_t,
    const float* __restrict__ bq, const float* __restrict__ bk,
    const float* __restrict__ bv, __bf16* __restrict__ qkv,
    const __bf16* __restrict__ Wc_t, const __bf16* __restrict__ Wob,
    __bf16* __restrict__ Wp_bt) {
  __shared__ __align__(16) __bf16 As[2][128 * 64];
  __shared__ __align__(16) __bf16 Bs[2][128 * 64];
  const int tid = threadIdx.x;
  const int w = tid >> 6, lane = tid & 63;
  const int wm = w & 1, wn = w >> 1;
  const int lm = lane & 15, quad = lane >> 4;
  const int srow = lane >> 3;                   // staging row-in-chunk
  const int scol = (((lane & 7) ^ srow) << 3);  // staging swizzled col
  const int lid = blockIdx.x;

  const __bf16 *Ap, *Bp;
  __bf16* op;
  int lda, ldo, m0, n0;
  bool dobias;
  if (lid < 1536) {
    const int xcd = lid & 7, chunk = lid >> 3;
    const int idx = xcd * 192 + chunk;
    const int mt = idx / 12, nt = idx - mt * 12;
    m0 = mt * 128; n0 = nt * 128;
    Ap = xb; lda = 512; Bp = Wqkv_t;
    op = qkv; ldo = 1536; dobias = true;
  } else {
    const int l2 = lid - 1536;
    const int z = l2 >> 4;
    m0 = ((l2 >> 2) & 3) * 128; n0 = (l2 & 3) * 128;
    Ap = Wc_t + z * 512; lda = 2048; Bp = Wob;
    op = Wp_bt + z * 512; ldo = 2048; dobias = false;
  }

  auto stage = [&](int buf, int k0) {
#pragma unroll
    for (int it = 0; it < 4; ++it) {
      const int c = w * 4 + it;
      const int row = c * 8 + srow;
      gld_lds16(Ap + (size_t)(m0 + row) * lda + k0 + scol, &As[buf][c * 512]);
      gld_lds16(Bp + (size_t)(n0 + row) * 512 + k0 + scol, &Bs[buf][c * 512]);
    }
  };

  f32x4 acc[4][4] = {};
  stage(0, 0);
  asm volatile("s_waitcnt vmcnt(0)" ::: "memory");
  __builtin_amdgcn_s_barrier();
  asm volatile("" ::: "memory");
  int cur = 0;
  for (int k0 = 0; k0 < 512; k0 += 64) {
    const bool more = (k0 + 64 < 512);
    if (more) stage(cur ^ 1, k0 + 64);  // next tile's loads fly under MFMA
    __builtin_amdgcn_s_setprio(1);
#pragma unroll
    for (int ks = 0; ks < 2; ++ks) {
      bf16x8 af[4], bfr[4];
#pragma unroll
      for (int i = 0; i < 4; ++i)
        af[i] = *(const bf16x8*)&As[cur][SWZ(wm * 64 + i * 16 + lm, ks * 4 + quad)];
#pragma unroll
      for (int j = 0; j < 4; ++j)
        bfr[j] = *(const bf16x8*)&Bs[cur][SWZ(wn * 64 + j * 16 + lm, ks * 4 + quad)];
#pragma unroll
      for (int i = 0; i < 4; ++i)
#pragma unroll
        for (int j = 0; j < 4; ++j)
          acc[i][j] = __builtin_amdgcn_mfma_f32_16x16x32_bf16(af[i], bfr[j], acc[i][j], 0, 0, 0);
    }
    __builtin_amdgcn_s_setprio(0);
    if (more) {
      asm volatile("s_waitcnt vmcnt(0)" ::: "memory");  // next tile landed
      __builtin_amdgcn_s_barrier();                     // single barrier/tile
      asm volatile("" ::: "memory");
    }
    cur ^= 1;
  }
#pragma unroll
  for (int j = 0; j < 4; ++j) {
    const int col = n0 + wn * 64 + j * 16 + lm;
    float bias = 0.f;
    if (dobias) {
      const int s = col >> 9;
      const float* bp = (s == 0) ? bq : (s == 1 ? bk : bv);
      bias = bp[col & 511];
    }
#pragma unroll
    for (int i = 0; i < 4; ++i) {
      const int row0 = m0 + wm * 64 + i * 16 + quad * 4;
#pragma unroll
      for (int r = 0; r < 4; ++r)
        op[(size_t)(row0 + r) * ldo + col] = (__bf16)(acc[i][j][r] + bias);
    }
  }
}

// ---------------------------------------------------------------------------
// Conv (Wo folded): K=2048 GEMM on cat with row gather, BK=64, swizzled LDS.
// R6 kernel (best measured): BM=64 x BN=128, grid (4,256) = 1024 blocks =
// 4 blocks/CU. Classic 2-barrier loop.
// Epilogue: per-tap bias suffix from bj[4][512], relu, +x (fp32), leaky_relu.
// ---------------------------------------------------------------------------
__global__ __launch_bounds__(256, 4) void conv_gemm_kernel(
    const __bf16* __restrict__ A,   // catb [16384][512]
    const __bf16* __restrict__ Bt,  // Wp_bt [512][2048]
    const float* __restrict__ bc, const float* __restrict__ bj,  // bj[4][512]
    const float* __restrict__ x, float* __restrict__ out,
    const __bf16* __restrict__ zeros) {
  __shared__ __align__(16) __bf16 As[64 * 64];    // 8 KB
  __shared__ __align__(16) __bf16 Bs[128 * 64];   // 16 KB
  const int tid = threadIdx.x;
  const int w = tid >> 6, lane = tid & 63;
  const int wm = w & 1, wn = w >> 1;   // 2M x 2N wave grid; wave tile 32x64
  const int lm = lane & 15, quad = lane >> 4;
  const int srow = lane >> 3;
  const int scol = (((lane & 7) ^ srow) << 3);
  const int lid = blockIdx.y * 4 + blockIdx.x;
  const int xcd = lid & 7, chunk = lid >> 3;
  const int idx = xcd * 128 + chunk;
  const int mt = idx >> 2, nt = idx & 3;
  const int m0 = mt * 64, n0 = nt * 128;

  f32x4 acc[2][4] = {};
  for (int k0 = 0; k0 < 4 * Cch; k0 += 64) {
    const int jtap = k0 >> 9;
    const int shift = 4 * jtap - 12;
    const int cin0 = k0 & 511;
    // A: 8 chunks of 8 rows (64 rows), 2 loads/thread
#pragma unroll
    for (int it = 0; it < 2; ++it) {
      const int c = w * 2 + it;
      const int row = c * 8 + srow;
      const int m = m0 + row;
      const __bf16* src = (((m & (Tseq - 1)) + shift) >= 0)
                              ? A + (size_t)(m + shift) * Cch + cin0 + scol
                              : zeros + scol;
      gld_lds16(src, &As[c * 512]);
    }
    // B: 16 chunks of 8 rows (128 rows), 4 loads/thread
#pragma unroll
    for (int it = 0; it < 4; ++it) {
      const int c = w * 4 + it;
      const int row = c * 8 + srow;
      gld_lds16(Bt + (size_t)(n0 + row) * 2048 + k0 + scol, &Bs[c * 512]);
    }
    __syncthreads();
#pragma unroll
    for (int ks = 0; ks < 2; ++ks) {
      bf16x8 af[2], bfr[4];
#pragma unroll
      for (int i = 0; i < 2; ++i)
        af[i] = *(const bf16x8*)&As[SWZ(wm * 32 + i * 16 + lm, ks * 4 + quad)];
#pragma unroll
      for (int j = 0; j < 4; ++j)
        bfr[j] = *(const bf16x8*)&Bs[SWZ(wn * 64 + j * 16 + lm, ks * 4 + quad)];
#pragma unroll
      for (int i = 0; i < 2; ++i)
#pragma unroll
        for (int j = 0; j < 4; ++j)
          acc[i][j] = __builtin_amdgcn_mfma_f32_16x16x32_bf16(af[i], bfr[j], acc[i][j], 0, 0, 0);
    }
    __syncthreads();
  }
#pragma unroll
  for (int j = 0; j < 4; ++j) {
    const int col = n0 + wn * 64 + j * 16 + lm;
    const float bcv = bc[col];
    float suf[4];
    suf[3] = bj[3 * 512 + col];
    suf[2] = suf[3] + bj[2 * 512 + col];
    suf[1] = suf[2] + bj[1 * 512 + col];
    suf[0] = suf[1] + bj[0 * 512 + col];
#pragma unroll
    for (int i = 0; i < 2; ++i) {
      const int row0 = m0 + wm * 32 + i * 16 + quad * 4;
#pragma unroll
      for (int r = 0; r < 4; ++r) {
        const int row = row0 + r;
        const int tl = row & (Tseq - 1);
        int jm = 15 - tl;
        jm = (jm < 0) ? 0 : (jm >> 2);
        float v = acc[i][j][r] + bcv + suf[jm];
        v = fmaxf(v, 0.f);
        v += x[(size_t)row * Cch + col];
        out[(size_t)row * Cch + col] = (v >= 0.f) ? v : 0.2f * v;
      }
    }
  }
}

// ---------------------------------------------------------------------------
// Banded attention, LDS-staged: one block per (b,h) x 64-t strip. Stage the
// 70 k-rows and 70 v-rows the strip needs into LDS once (35 KB), then 16-lane
// groups compute 4 t's each from LDS.
// ---------------------------------------------------------------------------
__global__ __launch_bounds__(256) void attn_band_kernel(
    const __bf16* __restrict__ qkv, __bf16* __restrict__ cat) {
  __shared__ __align__(16) __bf16 ks[70 * 128];
  __shared__ __align__(16) __bf16 vs[70 * 128];
  const int tid = threadIdx.x;
  const int bh = blockIdx.y;
  const int b = bh >> 2, h = bh & 3;
  const int t0 = blockIdx.x * 64;
  for (int c = tid; c < 70 * 16; c += 256) {
    const int row = c >> 4, chunk = c & 15;
    int s = t0 - 3 + row;
    s = (s < 0) ? 0 : ((s > Tseq - 1) ? Tseq - 1 : s);
    const __bf16* src = qkv + ((size_t)(b * Tseq + s)) * Nqkv + 512 + h * 128 + chunk * 8;
    *(bf16x8*)&ks[row * 128 + chunk * 8] = *(const bf16x8*)src;
    *(bf16x8*)&vs[row * 128 + chunk * 8] = *(const bf16x8*)(src + 512);
  }
  __syncthreads();
  const int g = tid & 15, grp = tid >> 4;
  const int d0 = g * 8;
  const float scale = 0.08838834764831845f;  // 1/sqrt(128)
#pragma unroll
  for (int tt = 0; tt < 4; ++tt) {
    const int tl = grp * 4 + tt;  // local t in [0,64)
    const int t = t0 + tl;
    bf16x8 qv = *(const bf16x8*)(qkv + ((size_t)(b * Tseq + t)) * Nqkv + h * 128 + d0);
    float score[7];
#pragma unroll
    for (int i = 0; i < 7; ++i) {
      const int s = t - 3 + i;
      const bool valid = (s >= 0) && (s < Tseq);
      bf16x8 kv = *(const bf16x8*)&ks[(tl + i) * 128 + d0];
      float p = 0.f;
#pragma unroll
      for (int e = 0; e < 8; ++e) p += (float)qv[e] * (float)kv[e];
      p += __shfl_xor(p, 1);
      p += __shfl_xor(p, 2);
      p += __shfl_xor(p, 4);
      p += __shfl_xor(p, 8);
      score[i] = valid ? p * scale : -1e30f;
    }
    float mx = score[0];
#pragma unroll
    for (int i = 1; i < 7; ++i) mx = fmaxf(mx, score[i]);
    float wgt[7], denom = 0.f;
#pragma unroll
    for (int i = 0; i < 7; ++i) {
      wgt[i] = (score[i] > -1e29f) ? expf(score[i] - mx) : 0.f;
      denom += wgt[i];
    }
    const float inv = 1.f / denom;
    float o[8] = {};
#pragma unroll
    for (int i = 0; i < 7; ++i) {
      bf16x8 vv = *(const bf16x8*)&vs[(tl + i) * 128 + d0];
#pragma unroll
      for (int e = 0; e < 8; ++e) o[e] += wgt[i] * (float)vv[e];
    }
    bf16x8 ov;
#pragma unroll
    for (int e = 0; e < 8; ++e) ov[e] = (__bf16)(o[e] * inv);
    *(bf16x8*)(cat + ((size_t)(b * Tseq + t)) * Cch + h * 128 + d0) = ov;
  }
}

// ---------------------------------------------------------------------------
// ONE prep kernel (flat grid):
//  [0,8192)       cast x -> xb (bf16)
//  [8192,8960)    transpose-cast Wq/Wk/Wv -> Wqkv_t [1536][512]
//  [8960,9984)    transpose-cast Wc (2048x512) -> Wc_t [512][2048]
//  [9984,10240)   cast Wo -> Wob (row-major)
//  10240          zero-fill zeros buffer
//  [10241,10273)  bias partials bj[j][n] = sum_ci bo[ci]*Wc[j,ci,n]
// ---------------------------------------------------------------------------
#define PREP_A 8192
#define PREP_B 8960
#define PREP_C 9984
#define PREP_D 10240
#define PREP_E 10241
#define PREP_N 10273

__global__ __launch_bounds__(256) void prep_kernel(
    const float* __restrict__ x, const float* __restrict__ Wq,
    const float* __restrict__ Wk, const float* __restrict__ Wv,
    const float* __restrict__ Wo, const float* __restrict__ Wc,
    const float* __restrict__ bo,
    __bf16* __restrict__ xb, __bf16* __restrict__ Wqkv_t,
    __bf16* __restrict__ Wc_t, __bf16* __restrict__ Wob,
    float* __restrict__ bj, __bf16* __restrict__ zeros) {
  __shared__ float sArr[32][33];
  __shared__ float red[256];
  const int bid = blockIdx.x;
  const int tid = threadIdx.x;
  if (bid < PREP_A) {
    const size_t i = ((size_t)bid * 256 + tid) * 4;
    float4 v = *(const float4*)(x + i);
    bf16x4 o;
    o[0] = (__bf16)v.x; o[1] = (__bf16)v.y; o[2] = (__bf16)v.z; o[3] = (__bf16)v.w;
    *(bf16x4*)(xb + i) = o;
  } else if (bid < PREP_B) {
    const int l = bid - PREP_A;
    const int bx = l & 3, by = (l >> 2) & 15, z = l >> 6;
    const int sgrp = z >> 2, h = z & 3;
    const float* src = ((sgrp == 0) ? Wq : (sgrp == 1) ? Wk : Wv) + h * (512 * 128);
    __bf16* dst = Wqkv_t + (size_t)z * 128 * 512;
    const int tx = tid & 31, ty = tid >> 5;
    const int c0 = bx * 32, r0 = by * 32;
#pragma unroll
    for (int rr = 0; rr < 4; ++rr)
      sArr[ty + rr * 8][tx] = src[(size_t)(r0 + ty + rr * 8) * 128 + c0 + tx];
    __syncthreads();
#pragma unroll
    for (int rr = 0; rr < 4; ++rr)
      dst[(size_t)(c0 + ty + rr * 8) * 512 + r0 + tx] = (__bf16)sArr[tx][ty + rr * 8];
  } else if (bid < PREP_C) {
    const int l = bid - PREP_B;
    const int bx = l & 15, by = l >> 4;
    const int tx = tid & 31, ty = tid >> 5;
    const int c0 = bx * 32, r0 = by * 32;
#pragma unroll
    for (int rr = 0; rr < 4; ++rr)
      sArr[ty + rr * 8][tx] = Wc[(size_t)(r0 + ty + rr * 8) * 512 + c0 + tx];
    __syncthreads();
#pragma unroll
    for (int rr = 0; rr < 4; ++rr)
      Wc_t[(size_t)(c0 + ty + rr * 8) * 2048 + r0 + tx] = (__bf16)sArr[tx][ty + rr * 8];
  } else if (bid < PREP_D) {
    const int l = bid - PREP_C;
    const size_t i = ((size_t)l * 256 + tid) * 4;
    float4 v = *(const float4*)(Wo + i);
    bf16x4 o;
    o[0] = (__bf16)v.x; o[1] = (__bf16)v.y; o[2] = (__bf16)v.z; o[3] = (__bf16)v.w;
    *(bf16x4*)(Wob + i) = o;
  } else if (bid < PREP_E) {
    bf16x8 zero = {};
    *(bf16x8*)(zeros + tid * 8) = zero;
  } else {
    const int l = bid - PREP_E;
    const int j = l >> 3, nb = l & 7;
    const int n = nb * 64 + (tid & 63);
    const int cig = tid >> 6;
    const float* base = Wc + ((size_t)j * 512 + cig * 128) * 512 + n;
    float acc = 0.f;
#pragma unroll 8
    for (int ci = 0; ci < 128; ++ci) acc += bo[cig * 128 + ci] * base[(size_t)ci * 512];
    red[tid] = acc;
    __syncthreads();
    if (tid < 64)
      bj[j * 512 + n] = red[tid] + red[tid + 64] + red[tid + 128] + red[tid + 192];
  }
}

// ---------------------------------------------------------------------------
extern "C" void kernel_launch(void* const* d_in, const int* in_sizes, int n_in,
                              void* d_out, int out_size, void* d_ws, size_t ws_size,
                              hipStream_t stream) {
  const float* x  = (const float*)d_in[0];
  const float* Wq = (const float*)d_in[1];
  const float* bq = (const float*)d_in[2];
  const float* Wk = (const float*)d_in[3];
  const float* bk = (const float*)d_in[4];
  const float* Wv = (const float*)d_in[5];
  const float* bv = (const float*)d_in[6];
  const float* Wo = (const float*)d_in[7];
  const float* bo = (const float*)d_in[8];
  const float* Wc = (const float*)d_in[9];
  const float* bc = (const float*)d_in[10];
  float* out = (float*)d_out;

  char* p = (char*)d_ws;
  __bf16* xb     = (__bf16*)p;  p += (size_t)Mrows * Cch * 2;    // 16 MiB
  __bf16* qkv    = (__bf16*)p;  p += (size_t)Mrows * Nqkv * 2;   // 48 MiB
  __bf16* catb   = (__bf16*)p;  p += (size_t)Mrows * Cch * 2;    // 16 MiB
  __bf16* Wqkv_t = (__bf16*)p;  p += (size_t)Nqkv * Cch * 2;     // 1.5 MiB
  __bf16* Wc_t   = (__bf16*)p;  p += (size_t)Cch * 2048 * 2;     // 2 MiB
  __bf16* Wob    = (__bf16*)p;  p += (size_t)Cch * Cch * 2;      // 0.5 MiB
  __bf16* Wp_bt  = (__bf16*)p;  p += (size_t)Cch * 2048 * 2;     // 2 MiB
  float*  bj     = (float*)p;   p += 4 * Cch * 4;                // 8 KiB
  __bf16* zeros  = (__bf16*)p;  p += 4096;

  prep_kernel<<<PREP_N, 256, 0, stream>>>(x, Wq, Wk, Wv, Wo, Wc, bo,
                                          xb, Wqkv_t, Wc_t, Wob, bj, zeros);

  // QKV projection + Wp = Wo @ Wc[j] precompute, fused into one launch
  gemm_qkv_wp_kernel<<<1600, 256, 0, stream>>>(xb, Wqkv_t, bq, bk, bv, qkv,
                                               Wc_t, Wob, Wp_bt);

  attn_band_kernel<<<dim3(Tseq / 64, Bb * 4), 256, 0, stream>>>(qkv, catb);

  conv_gemm_kernel<<<dim3(4, 256), 256, 0, stream>>>(
      catb, Wp_bt, bc, bj, x, out, zeros);
}

// Round 9
// 206.563 us; speedup vs baseline: 1.3325x; 1.0179x over previous
//
#include <hip/hip_runtime.h>
#include <math.h>

#define Bb    8
#define Tseq  2048
#define Cch   512
#define Mrows 16384
#define Nqkv  1536

typedef __bf16 bf16x8 __attribute__((ext_vector_type(8)));
typedef __bf16 bf16x4 __attribute__((ext_vector_type(4)));
typedef float  f32x4  __attribute__((ext_vector_type(4)));

__device__ __forceinline__ void gld_lds16(const void* g, void* l) {
  __builtin_amdgcn_global_load_lds(
      (const __attribute__((address_space(1))) unsigned int*)g,
      (__attribute__((address_space(3))) unsigned int*)l, 16, 0, 0);
}

// LDS bank-conflict-killing XOR swizzle: row r's 8-element group g lives at
// group (g ^ (r&7)). Verified: SQ_LDS_BANK_CONFLICT 1.26e7 -> 0.
#define SWZ(r, g) (((r) << 6) + ((((g) ^ ((r) & 7))) << 3))

// ---------------------------------------------------------------------------
// Round 15: qkv rebuilt on the R6 conv recipe (the only change that ever
// won in this session): BM=64 x BN=128, single 24KB LDS buffer, plain
// 2-barrier loop, 4+ blocks/CU. R8 evidence: qkv with the dbuf schedule ran
// 56.9us / MfmaUtil 17% / Occupancy 17% (LDS-capped at 2 blocks/CU) = 453 TF
// vs conv's 716 TF. Occupancy-by-grid is the lever, not scheduling.
// conv/attn/prep byte-identical to R8 (conv = best-measured 48.0us R6 kernel).
// ---------------------------------------------------------------------------

// ---------------------------------------------------------------------------
// Fused QKV-projection + Wp-precompute GEMM. BM=64 x BN=128.
// Blocks [0,3072): qkv = xb @ Wqkv_t^T + bias -> [16384][1536]
//   (256 mt x 12 nt, XCD-swizzled: consecutive chunks share the A-panel).
// Blocks [3072,3200): Wp[z] = Wc_t[:, z*512:] @ Wob^T -> Wp_bt [512][2048]
//   (4 z x 8 mt(64) x 4 nt(128)).
// ---------------------------------------------------------------------------
__global__ __launch_bounds__(256, 4) void gemm_qkv_wp_kernel(
    const __bf16* __restrict__ xb, const __bf16* __restrict__ Wqkv_t,
    const float* __restrict__ bq, const float* __restrict__ bk,
    const float* __restrict__ bv, __bf16* __restrict__ qkv,
    const __bf16* __restrict__ Wc_t, const __bf16* __restrict__ Wob,
    __bf16* __restrict__ Wp_bt) {
  __shared__ __align__(16) __bf16 As[64 * 64];    // 8 KB
  __shared__ __align__(16) __bf16 Bs[128 * 64];   // 16 KB
  const int tid = threadIdx.x;
  const int w = tid >> 6, lane = tid & 63;
  const int wm = w & 1, wn = w >> 1;   // 2M x 2N wave grid; wave tile 32x64
  const int lm = lane & 15, quad = lane >> 4;
  const int srow = lane >> 3;
  const int scol = (((lane & 7) ^ srow) << 3);
  const int lid = blockIdx.x;

  const __bf16 *Ap, *Bp;
  __bf16* op;
  int lda, ldo, m0, n0;
  bool dobias;
  if (lid < 3072) {
    const int xcd = lid & 7, chunk = lid >> 3;
    const int idx = xcd * 384 + chunk;
    const int mt = idx / 12, nt = idx - mt * 12;
    m0 = mt * 64; n0 = nt * 128;
    Ap = xb; lda = 512; Bp = Wqkv_t;
    op = qkv; ldo = 1536; dobias = true;
  } else {
    const int l2 = lid - 3072;            // [0,128)
    const int z = l2 >> 5;                // 4 taps
    const int rest = l2 & 31;
    m0 = (rest >> 2) * 64;                // 8 m-tiles over 512 rows
    n0 = (rest & 3) * 128;                // 4 n-tiles over 512 cols
    Ap = Wc_t + z * 512; lda = 2048; Bp = Wob;
    op = Wp_bt + z * 512; ldo = 2048; dobias = false;
  }

  f32x4 acc[2][4] = {};
  for (int k0 = 0; k0 < 512; k0 += 64) {
    // A: 8 chunks of 8 rows (64 rows), 2 loads/thread
#pragma unroll
    for (int it = 0; it < 2; ++it) {
      const int c = w * 2 + it;
      const int row = c * 8 + srow;
      gld_lds16(Ap + (size_t)(m0 + row) * lda + k0 + scol, &As[c * 512]);
    }
    // B: 16 chunks of 8 rows (128 rows), 4 loads/thread
#pragma unroll
    for (int it = 0; it < 4; ++it) {
      const int c = w * 4 + it;
      const int row = c * 8 + srow;
      gld_lds16(Bp + (size_t)(n0 + row) * 512 + k0 + scol, &Bs[c * 512]);
    }
    __syncthreads();
#pragma unroll
    for (int ks = 0; ks < 2; ++ks) {
      bf16x8 af[2], bfr[4];
#pragma unroll
      for (int i = 0; i < 2; ++i)
        af[i] = *(const bf16x8*)&As[SWZ(wm * 32 + i * 16 + lm, ks * 4 + quad)];
#pragma unroll
      for (int j = 0; j < 4; ++j)
        bfr[j] = *(const bf16x8*)&Bs[SWZ(wn * 64 + j * 16 + lm, ks * 4 + quad)];
#pragma unroll
      for (int i = 0; i < 2; ++i)
#pragma unroll
        for (int j = 0; j < 4; ++j)
          acc[i][j] = __builtin_amdgcn_mfma_f32_16x16x32_bf16(af[i], bfr[j], acc[i][j], 0, 0, 0);
    }
    __syncthreads();
  }
#pragma unroll
  for (int j = 0; j < 4; ++j) {
    const int col = n0 + wn * 64 + j * 16 + lm;
    float bias = 0.f;
    if (dobias) {
      const int s = col >> 9;
      const float* bp = (s == 0) ? bq : (s == 1 ? bk : bv);
      bias = bp[col & 511];
    }
#pragma unroll
    for (int i = 0; i < 2; ++i) {
      const int row0 = m0 + wm * 32 + i * 16 + quad * 4;
#pragma unroll
      for (int r = 0; r < 4; ++r)
        op[(size_t)(row0 + r) * ldo + col] = (__bf16)(acc[i][j][r] + bias);
    }
  }
}

// ---------------------------------------------------------------------------
// Conv (Wo folded): K=2048 GEMM on cat with row gather, BK=64, swizzled LDS.
// R6 kernel (best measured, 48.0us): BM=64 x BN=128, grid (4,256) = 1024
// blocks = 4 blocks/CU. Classic 2-barrier loop.
// Epilogue: per-tap bias suffix from bj[4][512], relu, +x (fp32), leaky_relu.
// ---------------------------------------------------------------------------
__global__ __launch_bounds__(256, 4) void conv_gemm_kernel(
    const __bf16* __restrict__ A,   // catb [16384][512]
    const __bf16* __restrict__ Bt,  // Wp_bt [512][2048]
    const float* __restrict__ bc, const float* __restrict__ bj,  // bj[4][512]
    const float* __restrict__ x, float* __restrict__ out,
    const __bf16* __restrict__ zeros) {
  __shared__ __align__(16) __bf16 As[64 * 64];    // 8 KB
  __shared__ __align__(16) __bf16 Bs[128 * 64];   // 16 KB
  const int tid = threadIdx.x;
  const int w = tid >> 6, lane = tid & 63;
  const int wm = w & 1, wn = w >> 1;   // 2M x 2N wave grid; wave tile 32x64
  const int lm = lane & 15, quad = lane >> 4;
  const int srow = lane >> 3;
  const int scol = (((lane & 7) ^ srow) << 3);
  const int lid = blockIdx.y * 4 + blockIdx.x;
  const int xcd = lid & 7, chunk = lid >> 3;
  const int idx = xcd * 128 + chunk;
  const int mt = idx >> 2, nt = idx & 3;
  const int m0 = mt * 64, n0 = nt * 128;

  f32x4 acc[2][4] = {};
  for (int k0 = 0; k0 < 4 * Cch; k0 += 64) {
    const int jtap = k0 >> 9;
    const int shift = 4 * jtap - 12;
    const int cin0 = k0 & 511;
    // A: 8 chunks of 8 rows (64 rows), 2 loads/thread
#pragma unroll
    for (int it = 0; it < 2; ++it) {
      const int c = w * 2 + it;
      const int row = c * 8 + srow;
      const int m = m0 + row;
      const __bf16* src = (((m & (Tseq - 1)) + shift) >= 0)
                              ? A + (size_t)(m + shift) * Cch + cin0 + scol
                              : zeros + scol;
      gld_lds16(src, &As[c * 512]);
    }
    // B: 16 chunks of 8 rows (128 rows), 4 loads/thread
#pragma unroll
    for (int it = 0; it < 4; ++it) {
      const int c = w * 4 + it;
      const int row = c * 8 + srow;
      gld_lds16(Bt + (size_t)(n0 + row) * 2048 + k0 + scol, &Bs[c * 512]);
    }
    __syncthreads();
#pragma unroll
    for (int ks = 0; ks < 2; ++ks) {
      bf16x8 af[2], bfr[4];
#pragma unroll
      for (int i = 0; i < 2; ++i)
        af[i] = *(const bf16x8*)&As[SWZ(wm * 32 + i * 16 + lm, ks * 4 + quad)];
#pragma unroll
      for (int j = 0; j < 4; ++j)
        bfr[j] = *(const bf16x8*)&Bs[SWZ(wn * 64 + j * 16 + lm, ks * 4 + quad)];
#pragma unroll
      for (int i = 0; i < 2; ++i)
#pragma unroll
        for (int j = 0; j < 4; ++j)
          acc[i][j] = __builtin_amdgcn_mfma_f32_16x16x32_bf16(af[i], bfr[j], acc[i][j], 0, 0, 0);
    }
    __syncthreads();
  }
#pragma unroll
  for (int j = 0; j < 4; ++j) {
    const int col = n0 + wn * 64 + j * 16 + lm;
    const float bcv = bc[col];
    float suf[4];
    suf[3] = bj[3 * 512 + col];
    suf[2] = suf[3] + bj[2 * 512 + col];
    suf[1] = suf[2] + bj[1 * 512 + col];
    suf[0] = suf[1] + bj[0 * 512 + col];
#pragma unroll
    for (int i = 0; i < 2; ++i) {
      const int row0 = m0 + wm * 32 + i * 16 + quad * 4;
#pragma unroll
      for (int r = 0; r < 4; ++r) {
        const int row = row0 + r;
        const int tl = row & (Tseq - 1);
        int jm = 15 - tl;
        jm = (jm < 0) ? 0 : (jm >> 2);
        float v = acc[i][j][r] + bcv + suf[jm];
        v = fmaxf(v, 0.f);
        v += x[(size_t)row * Cch + col];
        out[(size_t)row * Cch + col] = (v >= 0.f) ? v : 0.2f * v;
      }
    }
  }
}

// ---------------------------------------------------------------------------
// Banded attention, LDS-staged: one block per (b,h) x 64-t strip. Stage the
// 70 k-rows and 70 v-rows the strip needs into LDS once (35 KB), then 16-lane
// groups compute 4 t's each from LDS.
// ---------------------------------------------------------------------------
__global__ __launch_bounds__(256) void attn_band_kernel(
    const __bf16* __restrict__ qkv, __bf16* __restrict__ cat) {
  __shared__ __align__(16) __bf16 ks[70 * 128];
  __shared__ __align__(16) __bf16 vs[70 * 128];
  const int tid = threadIdx.x;
  const int bh = blockIdx.y;
  const int b = bh >> 2, h = bh & 3;
  const int t0 = blockIdx.x * 64;
  for (int c = tid; c < 70 * 16; c += 256) {
    const int row = c >> 4, chunk = c & 15;
    int s = t0 - 3 + row;
    s = (s < 0) ? 0 : ((s > Tseq - 1) ? Tseq - 1 : s);
    const __bf16* src = qkv + ((size_t)(b * Tseq + s)) * Nqkv + 512 + h * 128 + chunk * 8;
    *(bf16x8*)&ks[row * 128 + chunk * 8] = *(const bf16x8*)src;
    *(bf16x8*)&vs[row * 128 + chunk * 8] = *(const bf16x8*)(src + 512);
  }
  __syncthreads();
  const int g = tid & 15, grp = tid >> 4;
  const int d0 = g * 8;
  const float scale = 0.08838834764831845f;  // 1/sqrt(128)
#pragma unroll
  for (int tt = 0; tt < 4; ++tt) {
    const int tl = grp * 4 + tt;  // local t in [0,64)
    const int t = t0 + tl;
    bf16x8 qv = *(const bf16x8*)(qkv + ((size_t)(b * Tseq + t)) * Nqkv + h * 128 + d0);
    float score[7];
#pragma unroll
    for (int i = 0; i < 7; ++i) {
      const int s = t - 3 + i;
      const bool valid = (s >= 0) && (s < Tseq);
      bf16x8 kv = *(const bf16x8*)&ks[(tl + i) * 128 + d0];
      float p = 0.f;
#pragma unroll
      for (int e = 0; e < 8; ++e) p += (float)qv[e] * (float)kv[e];
      p += __shfl_xor(p, 1);
      p += __shfl_xor(p, 2);
      p += __shfl_xor(p, 4);
      p += __shfl_xor(p, 8);
      score[i] = valid ? p * scale : -1e30f;
    }
    float mx = score[0];
#pragma unroll
    for (int i = 1; i < 7; ++i) mx = fmaxf(mx, score[i]);
    float wgt[7], denom = 0.f;
#pragma unroll
    for (int i = 0; i < 7; ++i) {
      wgt[i] = (score[i] > -1e29f) ? expf(score[i] - mx) : 0.f;
      denom += wgt[i];
    }
    const float inv = 1.f / denom;
    float o[8] = {};
#pragma unroll
    for (int i = 0; i < 7; ++i) {
      bf16x8 vv = *(const bf16x8*)&vs[(tl + i) * 128 + d0];
#pragma unroll
      for (int e = 0; e < 8; ++e) o[e] += wgt[i] * (float)vv[e];
    }
    bf16x8 ov;
#pragma unroll
    for (int e = 0; e < 8; ++e) ov[e] = (__bf16)(o[e] * inv);
    *(bf16x8*)(cat + ((size_t)(b * Tseq + t)) * Cch + h * 128 + d0) = ov;
  }
}

// ---------------------------------------------------------------------------
// ONE prep kernel (flat grid):
//  [0,8192)       cast x -> xb (bf16)
//  [8192,8960)    transpose-cast Wq/Wk/Wv -> Wqkv_t [1536][512]
//  [8960,9984)    transpose-cast Wc (2048x512) -> Wc_t [512][2048]
//  [9984,10240)   cast Wo -> Wob (row-major)
//  10240          zero-fill zeros buffer
//  [10241,10273)  bias partials bj[j][n] = sum_ci bo[ci]*Wc[j,ci,n]
// ---------------------------------------------------------------------------
#define PREP_A 8192
#define PREP_B 8960
#define PREP_C 9984
#define PREP_D 10240
#define PREP_E 10241
#define PREP_N 10273

__global__ __launch_bounds__(256) void prep_kernel(
    const float* __restrict__ x, const float* __restrict__ Wq,
    const float* __restrict__ Wk, const float* __restrict__ Wv,
    const float* __restrict__ Wo, const float* __restrict__ Wc,
    const float* __restrict__ bo,
    __bf16* __restrict__ xb, __bf16* __restrict__ Wqkv_t,
    __bf16* __restrict__ Wc_t, __bf16* __restrict__ Wob,
    float* __restrict__ bj, __bf16* __restrict__ zeros) {
  __shared__ float sArr[32][33];
  __shared__ float red[256];
  const int bid = blockIdx.x;
  const int tid = threadIdx.x;
  if (bid < PREP_A) {
    const size_t i = ((size_t)bid * 256 + tid) * 4;
    float4 v = *(const float4*)(x + i);
    bf16x4 o;
    o[0] = (__bf16)v.x; o[1] = (__bf16)v.y; o[2] = (__bf16)v.z; o[3] = (__bf16)v.w;
    *(bf16x4*)(xb + i) = o;
  } else if (bid < PREP_B) {
    const int l = bid - PREP_A;
    const int bx = l & 3, by = (l >> 2) & 15, z = l >> 6;
    const int sgrp = z >> 2, h = z & 3;
    const float* src = ((sgrp == 0) ? Wq : (sgrp == 1) ? Wk : Wv) + h * (512 * 128);
    __bf16* dst = Wqkv_t + (size_t)z * 128 * 512;
    const int tx = tid & 31, ty = tid >> 5;
    const int c0 = bx * 32, r0 = by * 32;
#pragma unroll
    for (int rr = 0; rr < 4; ++rr)
      sArr[ty + rr * 8][tx] = src[(size_t)(r0 + ty + rr * 8) * 128 + c0 + tx];
    __syncthreads();
#pragma unroll
    for (int rr = 0; rr < 4; ++rr)
      dst[(size_t)(c0 + ty + rr * 8) * 512 + r0 + tx] = (__bf16)sArr[tx][ty + rr * 8];
  } else if (bid < PREP_C) {
    const int l = bid - PREP_B;
    const int bx = l & 15, by = l >> 4;
    const int tx = tid & 31, ty = tid >> 5;
    const int c0 = bx * 32, r0 = by * 32;
#pragma unroll
    for (int rr = 0; rr < 4; ++rr)
      sArr[ty + rr * 8][tx] = Wc[(size_t)(r0 + ty + rr * 8) * 512 + c0 + tx];
    __syncthreads();
#pragma unroll
    for (int rr = 0; rr < 4; ++rr)
      Wc_t[(size_t)(c0 + ty + rr * 8) * 2048 + r0 + tx] = (__bf16)sArr[tx][ty + rr * 8];
  } else if (bid < PREP_D) {
    const int l = bid - PREP_C;
    const size_t i = ((size_t)l * 256 + tid) * 4;
    float4 v = *(const float4*)(Wo + i);
    bf16x4 o;
    o[0] = (__bf16)v.x; o[1] = (__bf16)v.y; o[2] = (__bf16)v.z; o[3] = (__bf16)v.w;
    *(bf16x4*)(Wob + i) = o;
  } else if (bid < PREP_E) {
    bf16x8 zero = {};
    *(bf16x8*)(zeros + tid * 8) = zero;
  } else {
    const int l = bid - PREP_E;
    const int j = l >> 3, nb = l & 7;
    const int n = nb * 64 + (tid & 63);
    const int cig = tid >> 6;
    const float* base = Wc + ((size_t)j * 512 + cig * 128) * 512 + n;
    float acc = 0.f;
#pragma unroll 8
    for (int ci = 0; ci < 128; ++ci) acc += bo[cig * 128 + ci] * base[(size_t)ci * 512];
    red[tid] = acc;
    __syncthreads();
    if (tid < 64)
      bj[j * 512 + n] = red[tid] + red[tid + 64] + red[tid + 128] + red[tid + 192];
  }
}

// ---------------------------------------------------------------------------
extern "C" void kernel_launch(void* const* d_in, const int* in_sizes, int n_in,
                              void* d_out, int out_size, void* d_ws, size_t ws_size,
                              hipStream_t stream) {
  const float* x  = (const float*)d_in[0];
  const float* Wq = (const float*)d_in[1];
  const float* bq = (const float*)d_in[2];
  const float* Wk = (const float*)d_in[3];
  const float* bk = (const float*)d_in[4];
  const float* Wv = (const float*)d_in[5];
  const float* bv = (const float*)d_in[6];
  const float* Wo = (const float*)d_in[7];
  const float* bo = (const float*)d_in[8];
  const float* Wc = (const float*)d_in[9];
  const float* bc = (const float*)d_in[10];
  float* out = (float*)d_out;

  char* p = (char*)d_ws;
  __bf16* xb     = (__bf16*)p;  p += (size_t)Mrows * Cch * 2;    // 16 MiB
  __bf16* qkv    = (__bf16*)p;  p += (size_t)Mrows * Nqkv * 2;   // 48 MiB
  __bf16* catb   = (__bf16*)p;  p += (size_t)Mrows * Cch * 2;    // 16 MiB
  __bf16* Wqkv_t = (__bf16*)p;  p += (size_t)Nqkv * Cch * 2;     // 1.5 MiB
  __bf16* Wc_t   = (__bf16*)p;  p += (size_t)Cch * 2048 * 2;     // 2 MiB
  __bf16* Wob    = (__bf16*)p;  p += (size_t)Cch * Cch * 2;      // 0.5 MiB
  __bf16* Wp_bt  = (__bf16*)p;  p += (size_t)Cch * 2048 * 2;     // 2 MiB
  float*  bj     = (float*)p;   p += 4 * Cch * 4;                // 8 KiB
  __bf16* zeros  = (__bf16*)p;  p += 4096;

  prep_kernel<<<PREP_N, 256, 0, stream>>>(x, Wq, Wk, Wv, Wo, Wc, bo,
                                          xb, Wqkv_t, Wc_t, Wob, bj, zeros);

  // QKV projection + Wp = Wo @ Wc[j] precompute, fused into one launch
  gemm_qkv_wp_kernel<<<3200, 256, 0, stream>>>(xb, Wqkv_t, bq, bk, bv, qkv,
                                               Wc_t, Wob, Wp_bt);

  attn_band_kernel<<<dim3(Tseq / 64, Bb * 4), 256, 0, stream>>>(qkv, catb);

  conv_gemm_kernel<<<dim3(4, 256), 256, 0, stream>>>(
      catb, Wp_bt, bc, bj, x, out, zeros);
}